// Round 2
// baseline (44.465 us; speedup 1.0000x reference)
//
#include <hip/hip_runtime.h>
#include <hip/hip_bf16.h>

// Sizes (fixed by the problem)
#define VOCAB 50257
#define EMB   1024
#define HID   1024
#define OUTV  50257

// All float tensors are float32 on device (per reference dtypes; confirmed by
// in_npz size ~412MB ~= f32 total 446MB compressed; bf16 reinterpretation in
// round 1 produced NaN from random mantissa bit patterns).

__device__ __forceinline__ float wave_reduce(float v) {
    #pragma unroll
    for (int off = 32; off > 0; off >>= 1) v += __shfl_xor(v, off);
    return v;
}

__device__ __forceinline__ float dot4(float4 a, float4 b) {
    return a.x * b.x + a.y * b.y + a.z * b.z + a.w * b.w;
}

// Kernel 1: m[r] = alpha[r]*gx*gh + beta1[r]*gx + beta2[r]*gh  for r in [0,4096)
// gx = Wx[r,:].x + bx[r],  gh = Wh[r,:].h0 + bh[r]
// one wave per row; 4 waves/block; 1024 blocks
__global__ __launch_bounds__(256) void k_gates(
        const int* __restrict__ inp,
        const float* __restrict__ emb,
        const float* __restrict__ Wx, const float* __restrict__ bx,
        const float* __restrict__ Wh, const float* __restrict__ bh,
        const float* __restrict__ h0,
        const float* __restrict__ alpha, const float* __restrict__ beta1,
        const float* __restrict__ beta2,
        float* __restrict__ m_ws) {
    const int wave = threadIdx.x >> 6;
    const int lane = threadIdx.x & 63;
    const int r = blockIdx.x * 4 + wave;            // row 0..4095

    const size_t x_off = (size_t)inp[0] * (size_t)EMB;
    const float* wx_row = Wx + (size_t)r * EMB;
    const float* wh_row = Wh + (size_t)r * HID;

    float accx = 0.f, acch = 0.f;
    #pragma unroll
    for (int s = 0; s < 4; ++s) {
        const int c = s * 256 + lane * 4;           // 4 floats (16B) per lane
        float4 wxv = *(const float4*)(wx_row + c);
        float4 xv  = *(const float4*)(emb + x_off + c);
        float4 whv = *(const float4*)(wh_row + c);
        float4 hv  = *(const float4*)(h0 + c);
        accx += dot4(wxv, xv);
        acch += dot4(whv, hv);
    }
    accx = wave_reduce(accx);
    acch = wave_reduce(acch);

    if (lane == 0) {
        float gx = accx + bx[r];
        float gh = acch + bh[r];
        m_ws[r] = alpha[r] * gx * gh + beta1[r] * gx + beta2[r] * gh;
    }
}

// Kernel 2: gates -> cx, hx. 1024 threads total.
__global__ __launch_bounds__(256) void k_cell(
        const float* __restrict__ m_ws,
        const float* __restrict__ c0,
        float* __restrict__ hx_ws,
        float* __restrict__ out_hx, float* __restrict__ out_cx) {
    const int j = blockIdx.x * 256 + threadIdx.x;   // 0..1023
    float m0 = m_ws[j];
    float m1 = m_ws[HID + j];
    float m2 = m_ws[2 * HID + j];
    float m3 = m_ws[3 * HID + j];
    float fg = 1.f / (1.f + expf(-m0));
    float ig = 1.f / (1.f + expf(-m1));
    float og = 1.f / (1.f + expf(-m2));
    float zt = tanhf(m3);
    float c  = fg * c0[j] + ig * zt;
    float h  = og * tanhf(c);
    hx_ws[j]  = h;
    out_hx[j] = h;
    out_cx[j] = c;
}

// Kernel 3: out[r] = Wdec[r,:] . hx + bdec[r]; wave per row, hx staged in LDS
__global__ __launch_bounds__(256) void k_dec(
        const float* __restrict__ hx_ws,
        const float* __restrict__ Wdec, const float* __restrict__ bdec,
        float* __restrict__ out) {
    __shared__ float xs[HID];
    for (int t = threadIdx.x; t < HID; t += 256) xs[t] = hx_ws[t];
    __syncthreads();

    const int wave = threadIdx.x >> 6;
    const int lane = threadIdx.x & 63;
    const int r = blockIdx.x * 4 + wave;
    if (r >= OUTV) return;

    const float* wrow = Wdec + (size_t)r * HID;
    float acc = 0.f;
    #pragma unroll
    for (int s = 0; s < 4; ++s) {
        const int c = s * 256 + lane * 4;
        float4 w = *(const float4*)(wrow + c);
        float4 x = *(const float4*)(xs + c);
        acc += dot4(w, x);
    }
    acc = wave_reduce(acc);
    if (lane == 0) out[r] = acc + bdec[r];
}

extern "C" void kernel_launch(void* const* d_in, const int* in_sizes, int n_in,
                              void* d_out, int out_size, void* d_ws, size_t ws_size,
                              hipStream_t stream) {
    const int*   inp   = (const int*)d_in[0];
    const float* h0    = (const float*)d_in[1];
    const float* c0    = (const float*)d_in[2];
    const float* emb   = (const float*)d_in[3];
    const float* Wx    = (const float*)d_in[4];
    const float* bx    = (const float*)d_in[5];
    const float* Wh    = (const float*)d_in[6];
    const float* bh    = (const float*)d_in[7];
    const float* alpha = (const float*)d_in[8];
    const float* beta1 = (const float*)d_in[9];
    const float* beta2 = (const float*)d_in[10];
    const float* Wdec  = (const float*)d_in[11];
    const float* bdec  = (const float*)d_in[12];

    float* out = (float*)d_out;               // [0,50257): out, then hx[1024], cx[1024]
    float* m_ws  = (float*)d_ws;              // 4096 f32
    float* hx_ws = m_ws + 4 * HID;            // 1024 f32

    k_gates<<<1024, 256, 0, stream>>>(inp, emb, Wx, bx, Wh, bh, h0,
                                      alpha, beta1, beta2, m_ws);
    k_cell<<<4, 256, 0, stream>>>(m_ws, c0, hx_ws, out + OUTV, out + OUTV + HID);
    k_dec<<<(OUTV + 3) / 4, 256, 0, stream>>>(hx_ws, Wdec, bdec, out);
}

// Round 3
// 42.885 us; speedup vs baseline: 1.0369x; 1.0369x over previous
//
#include <hip/hip_runtime.h>
#include <hip/hip_bf16.h>

// Sizes (fixed by the problem)
#define VOCAB 50257
#define EMB   1024
#define HID   1024
#define OUTV  50257

// All float tensors are float32 on device (confirmed round 2: passed with
// absmax 2e-3; in_npz ~412MB ~= f32 total).

__device__ __forceinline__ float wave_reduce(float v) {
    #pragma unroll
    for (int off = 32; off > 0; off >>= 1) v += __shfl_xor(v, off);
    return v;
}

__device__ __forceinline__ float dot4(float4 a, float4 b) {
    return a.x * b.x + a.y * b.y + a.z * b.z + a.w * b.w;
}

// Kernel 1 (fused gates + cell): block j = hidden unit j (1024 blocks).
// Wave g (g=0..3) computes gate row r = g*HID + j:
//   gx = Wx[r,:].x + bx[r], gh = Wh[r,:].h0 + bh[r]
//   m  = alpha[r]*gx*gh + beta1[r]*gx + beta2[r]*gh
// Then thread 0 applies the cell nonlinearity and writes hx/cx.
__global__ __launch_bounds__(256) void k_gates_cell(
        const int* __restrict__ inp,
        const float* __restrict__ emb,
        const float* __restrict__ Wx, const float* __restrict__ bx,
        const float* __restrict__ Wh, const float* __restrict__ bh,
        const float* __restrict__ h0,
        const float* __restrict__ alpha, const float* __restrict__ beta1,
        const float* __restrict__ beta2,
        const float* __restrict__ c0,
        float* __restrict__ hx_ws,
        float* __restrict__ out_hx, float* __restrict__ out_cx) {
    __shared__ float m_s[4];

    const int g    = threadIdx.x >> 6;              // gate 0..3 (f,i,o,z)
    const int lane = threadIdx.x & 63;
    const int j    = blockIdx.x;                    // hidden unit
    const int r    = g * HID + j;                   // gate row in [0,4096)

    const size_t x_off = (size_t)inp[0] * (size_t)EMB;
    const float* wx_row = Wx + (size_t)r * EMB;
    const float* wh_row = Wh + (size_t)r * HID;

    float accx = 0.f, acch = 0.f;
    #pragma unroll
    for (int s = 0; s < 4; ++s) {
        const int c = s * 256 + lane * 4;           // 4 floats (16B) per lane
        float4 wxv = *(const float4*)(wx_row + c);
        float4 xv  = *(const float4*)(emb + x_off + c);
        float4 whv = *(const float4*)(wh_row + c);
        float4 hv  = *(const float4*)(h0 + c);
        accx += dot4(wxv, xv);
        acch += dot4(whv, hv);
    }
    accx = wave_reduce(accx);
    acch = wave_reduce(acch);

    if (lane == 0) {
        float gx = accx + bx[r];
        float gh = acch + bh[r];
        m_s[g] = alpha[r] * gx * gh + beta1[r] * gx + beta2[r] * gh;
    }
    __syncthreads();

    if (threadIdx.x == 0) {
        float fg = 1.f / (1.f + expf(-m_s[0]));
        float ig = 1.f / (1.f + expf(-m_s[1]));
        float og = 1.f / (1.f + expf(-m_s[2]));
        float zt = tanhf(m_s[3]);
        float c  = fg * c0[j] + ig * zt;
        float h  = og * tanhf(c);
        hx_ws[j]  = h;
        out_hx[j] = h;
        out_cx[j] = c;
    }
}

// Kernel 2: out[r] = Wdec[r,:] . hx + bdec[r]; wave per row, hx staged in LDS
__global__ __launch_bounds__(256) void k_dec(
        const float* __restrict__ hx_ws,
        const float* __restrict__ Wdec, const float* __restrict__ bdec,
        float* __restrict__ out) {
    __shared__ float xs[HID];
    for (int t = threadIdx.x; t < HID; t += 256) xs[t] = hx_ws[t];
    __syncthreads();

    const int wave = threadIdx.x >> 6;
    const int lane = threadIdx.x & 63;
    const int r = blockIdx.x * 4 + wave;
    if (r >= OUTV) return;

    const float* wrow = Wdec + (size_t)r * HID;
    float acc = 0.f;
    #pragma unroll
    for (int s = 0; s < 4; ++s) {
        const int c = s * 256 + lane * 4;
        float4 w = *(const float4*)(wrow + c);
        float4 x = *(const float4*)(xs + c);
        acc += dot4(w, x);
    }
    acc = wave_reduce(acc);
    if (lane == 0) out[r] = acc + bdec[r];
}

extern "C" void kernel_launch(void* const* d_in, const int* in_sizes, int n_in,
                              void* d_out, int out_size, void* d_ws, size_t ws_size,
                              hipStream_t stream) {
    const int*   inp   = (const int*)d_in[0];
    const float* h0    = (const float*)d_in[1];
    const float* c0    = (const float*)d_in[2];
    const float* emb   = (const float*)d_in[3];
    const float* Wx    = (const float*)d_in[4];
    const float* bx    = (const float*)d_in[5];
    const float* Wh    = (const float*)d_in[6];
    const float* bh    = (const float*)d_in[7];
    const float* alpha = (const float*)d_in[8];
    const float* beta1 = (const float*)d_in[9];
    const float* beta2 = (const float*)d_in[10];
    const float* Wdec  = (const float*)d_in[11];
    const float* bdec  = (const float*)d_in[12];

    float* out   = (float*)d_out;              // [0,50257): out, then hx[1024], cx[1024]
    float* hx_ws = (float*)d_ws;               // 1024 f32

    k_gates_cell<<<1024, 256, 0, stream>>>(inp, emb, Wx, bx, Wh, bh, h0,
                                           alpha, beta1, beta2, c0,
                                           hx_ws, out + OUTV, out + OUTV + HID);
    k_dec<<<(OUTV + 3) / 4, 256, 0, stream>>>(hx_ws, Wdec, bdec, out);
}